// Round 2
// baseline (628.380 us; speedup 1.0000x reference)
//
#include <hip/hip_runtime.h>
#include <stdint.h>

#define NB 8
#define NA 100000
#define NC 80
#define NM 50
#define NH 512
#define NW 512
#define J_PER_S (NA * (NC / 4))   // 2,000,000 float4s per sample

// ws layout: floats [0..7]=cls_sum [8..15]=xy_sum [16..23]=ang_sum [24..31]=npos
//            [32] (int) = states-layout flag
//            byte offset 4096: int codes[NB*NA]  (low16 sext = code, bit16 = gt)

__global__ void detect_states_layout(const uint32_t* __restrict__ w, int* __restrict__ flag) {
    // Packed-uint8 bools -> words with all bytes in {0,1} and value > 1.
    // int32 bools (0/1) and fp32 bools (0x3F800000) never match.
    uint32_t ev = 0;
    for (int j = threadIdx.x; j < 65536; j += 256) {
        uint32_t v = w[j];
        if (((v & 0xFEFEFEFEu) == 0u) && (v > 1u)) ev = 1u;
    }
    if (ev) atomicOr(flag, 1);
}

__global__ __launch_bounds__(256) void focal_assign(
    const float* __restrict__ reg,   // (B, A, 3)
    const float* __restrict__ anch,  // (1, A, 3)
    const float* __restrict__ ann,   // (B, M, 4)
    const void*  __restrict__ states,// (B, 1, H, W) bool
    const int*   __restrict__ flag,
    float* __restrict__ acc,
    int*   __restrict__ codes)
{
    __shared__ float4 sann[NM];
    __shared__ float  sred[3];   // [0]=npos [1]=xy [2]=ang

    const int t = threadIdx.x;
    const int b = blockIdx.y;
    const int i = blockIdx.x * 256 + t;

    if (t < NM) sann[t] = ((const float4*)(ann + (size_t)b * NM * 4))[t];
    if (t < 3)  sred[t] = 0.0f;
    __syncthreads();

    if (i < NA) {
        const float ax  = anch[3 * i + 0];
        const float ay  = anch[3 * i + 1];
        const float aal = anch[3 * i + 2];

        float d2min = 1e30f;
        int   mmin  = 0;
        #pragma unroll 10
        for (int m = 0; m < NM; ++m) {
            float4 a4 = sann[m];
            float dx = ax - a4.x, dy = ay - a4.y;
            float d2 = dx * dx + dy * dy;
            if (d2 < d2min) { d2min = d2; mmin = m; }
        }
        float4 am  = sann[mmin];
        float dxy  = sqrtf(d2min);
        float dal  = fabsf(aal - am.z);
        bool pos = (dxy <= 5.0f) && (dal <= 10.0f);
        bool neg = (dxy >= 7.5f) || (dal >= 15.0f);
        int code = pos ? (int)am.w : (neg ? -1 : -2);

        const int ix = (int)rintf(ax);   // jnp.round = half-to-even
        const int iy = (int)rintf(ay);
        const size_t sidx = (size_t)b * NH * NW + (size_t)iy * NW + ix;
        bool gt;
        if (*flag & 1) gt = ((const uint8_t*)states)[sidx] != 0;
        else           gt = ((const uint32_t*)states)[sidx] != 0u;

        codes[(size_t)b * NA + i] = (code & 0xFFFF) | (gt ? 0x10000 : 0);

        if (pos) {
            const float damp = gt ? 1.0f : 0.1f;
            const float* r = reg + ((size_t)b * NA + i) * 3;
            const float r0 = r[0], r1 = r[1], r2 = r[2];
            const float tdx = am.x - ax, tdy = am.y - ay, tda = am.z - aal;
            const float dxr = fabsf(tdx - r0);
            const float dyr = fabsf(tdy - r1);
            const float lx = (dxr <= (1.0f / 9.0f)) ? 4.5f * dxr * dxr : dxr - (0.5f / 9.0f);
            const float ly = (dyr <= (1.0f / 9.0f)) ? 4.5f * dyr * dyr : dyr - (0.5f / 9.0f);
            atomicAdd(&sred[0], 1.0f);
            atomicAdd(&sred[1], (lx + ly) * damp);
            atomicAdd(&sred[2], fmaxf((fabsf(tda - r2) - 10.0f) / 5.0f, 0.0f) * damp);
        }
    }
    __syncthreads();
    if (t == 0 && sred[0] != 0.0f) {
        atomicAdd(&acc[24 + b], sred[0]);
        atomicAdd(&acc[8 + b],  sred[1]);
        atomicAdd(&acc[16 + b], sred[2]);
    }
}

__device__ __forceinline__ float clampp(float p) {
    return fminf(fmaxf(p, 1e-4f), 0.9999f);
}

__global__ __launch_bounds__(256) void focal_cls(
    const float* __restrict__ cls,    // (B, A, C)
    const int*   __restrict__ codes,  // (B, A) packed
    float* __restrict__ acc)
{
    const int t = threadIdx.x;
    const int b = blockIdx.y;
    const unsigned j0 = blockIdx.x * 1024u + (unsigned)t;

    const float4* cbase = (const float4*)(cls + (size_t)b * NA * NC);
    const int*    cd    = codes + (size_t)b * NA;

    // ---- batch phase: issue all 8 loads before any compute ----
    unsigned jc[4];
    unsigned ia[4];
    int      pk[4];
    float4   v[4];
    bool     valid[4];
    #pragma unroll
    for (int k = 0; k < 4; ++k) {
        unsigned j = j0 + (unsigned)k * 256u;
        valid[k] = j < (unsigned)J_PER_S;
        jc[k] = valid[k] ? j : (unsigned)(J_PER_S - 1);
        ia[k] = jc[k] / 20u;
        pk[k] = cd[ia[k]];
        v[k]  = cbase[jc[k]];
    }

    float sM = 0.0f;   // sum of w * p^2 * log(1-p)   (negative; x -0.05 at end)
    float s2 = 0.0f;   // rare pos-element corrections
    #pragma unroll
    for (int k = 0; k < 4; ++k) {
        const int   c  = (int)((pk[k] << 16) >> 16);         // sext low16
        float w  = (c == -2) ? 0.0f : ((pk[k] & 0x10000) ? 1.0f : 0.1f);
        if (!valid[k]) w = 0.0f;
        const int   cb = (int)(jc[k] - ia[k] * 20u) * 4;

        const float px = clampp(v[k].x), py = clampp(v[k].y);
        const float pz = clampp(v[k].z), pw = clampp(v[k].w);
        float s4;
        s4  = px * px * __logf(1.0f - px);
        s4 += py * py * __logf(1.0f - py);
        s4 += pz * pz * __logf(1.0f - pz);
        s4 += pw * pw * __logf(1.0f - pw);
        sM += w * s4;

        const int e = c - cb;
        if ((unsigned)e < 4u) {   // rare: this float4 holds the pos target class
            const float pe = (e < 2) ? (e == 0 ? px : py) : (e == 2 ? pz : pw);
            const float om = 1.0f - pe;
            s2 += w * (0.95f * om * om * (-__logf(pe)) - 0.05f * pe * pe * (-__logf(om)));
        }
    }

    float vsum = -0.05f * sM + s2;
    #pragma unroll
    for (int o = 32; o > 0; o >>= 1) vsum += __shfl_down(vsum, o, 64);

    __shared__ float wred[4];
    if ((t & 63) == 0) wred[t >> 6] = vsum;
    __syncthreads();
    if (t == 0) {
        atomicAdd(&acc[b], wred[0] + wred[1] + wred[2] + wred[3]);
    }
}

__global__ void focal_final(const float* __restrict__ acc, float* __restrict__ out) {
    if (threadIdx.x == 0) {
        float c = 0.0f, x = 0.0f, a = 0.0f;
        for (int b = 0; b < NB; ++b) {
            float np = acc[24 + b];
            c += acc[b] / fmaxf(np, 1.0f);
            if (np > 0.0f) {
                x += acc[8 + b]  / (2.0f * np);
                a += acc[16 + b] / np;
            }
        }
        out[0] = c / (float)NB;
        out[1] = x / (float)NB;
        out[2] = a / (float)NB;
    }
}

extern "C" void kernel_launch(void* const* d_in, const int* in_sizes, int n_in,
                              void* d_out, int out_size, void* d_ws, size_t ws_size,
                              hipStream_t stream) {
    const float* cls    = (const float*)d_in[0];
    const float* reg    = (const float*)d_in[1];
    const float* anch   = (const float*)d_in[2];
    const float* ann    = (const float*)d_in[3];
    const void*  states = d_in[4];

    float* acc   = (float*)d_ws;
    int*   flag  = (int*)((float*)d_ws + 32);
    int*   codes = (int*)((char*)d_ws + 4096);

    hipMemsetAsync(d_ws, 0, 256, stream);
    detect_states_layout<<<1, 256, 0, stream>>>((const uint32_t*)states, flag);

    dim3 gridA((NA + 255) / 256, NB);
    focal_assign<<<gridA, 256, 0, stream>>>(reg, anch, ann, states, flag, acc, codes);

    dim3 gridB((J_PER_S + 1023) / 1024, NB);
    focal_cls<<<gridB, 256, 0, stream>>>(cls, codes, acc);

    focal_final<<<1, 64, 0, stream>>>(acc, (float*)d_out);
}

// Round 3
// 519.863 us; speedup vs baseline: 1.2087x; 1.2087x over previous
//
#include <hip/hip_runtime.h>
#include <stdint.h>

#define NB 8
#define NA 100000
#define NC 80
#define NM 50
#define NH 512
#define NW 512
#define J_PER_S (NA * (NC / 4))     // 2,000,000 float4s per sample

#define CLS_TILE 4096               // float4s per focal_cls block (256 thr x 16)
#define GX_CLS  ((J_PER_S + CLS_TILE - 1) / CLS_TILE)   // 489 blocks per sample
#define GX_ASG  ((NA + 255) / 256)                      // 391 blocks per sample
#define PSTRIDE 512                 // partial-array row stride (>= max(GX_CLS,GX_ASG))

// ws layout (float* w = d_ws):
//   w[32] (as int)            : states-layout flag
//   w+1024  (int[NB*NA])      : packed codes (low16 sext = class, bit16 = gt)
//   P = w + 1024 + NB*NA      : partials
//     P + 0*8*PSTRIDE : P_cls [NB][PSTRIDE]
//     P + 1*8*PSTRIDE : P_npos[NB][PSTRIDE]
//     P + 2*8*PSTRIDE : P_xy  [NB][PSTRIDE]
//     P + 3*8*PSTRIDE : P_ang [NB][PSTRIDE]

__global__ void detect_states_layout(const uint32_t* __restrict__ w, int* __restrict__ flag) {
    // Packed-uint8 bools -> words with all bytes in {0,1} and value > 1.
    // int32 bools (0/1) and fp32 bools (0x3F800000) never match.
    uint32_t ev = 0;
    for (int j = threadIdx.x; j < 65536; j += 256) {
        uint32_t v = w[j];
        if (((v & 0xFEFEFEFEu) == 0u) && (v > 1u)) ev = 1u;
    }
    if (ev) atomicOr(flag, 1);
}

__global__ __launch_bounds__(256) void focal_assign(
    const float* __restrict__ reg,   // (B, A, 3)
    const float* __restrict__ anch,  // (1, A, 3)
    const float* __restrict__ ann,   // (B, M, 4)
    const void*  __restrict__ states,// (B, 1, H, W) bool
    const int*   __restrict__ flag,
    float* __restrict__ P,           // partials base
    int*   __restrict__ codes)
{
    __shared__ float4 sann[NM];
    __shared__ float  sred[3];   // [0]=npos [1]=xy [2]=ang  (LDS atomics only)

    const int t = threadIdx.x;
    const int b = blockIdx.y;
    const int i = blockIdx.x * 256 + t;

    if (t < NM) sann[t] = ((const float4*)(ann + (size_t)b * NM * 4))[t];
    if (t < 3)  sred[t] = 0.0f;
    __syncthreads();

    if (i < NA) {
        const float ax  = anch[3 * i + 0];
        const float ay  = anch[3 * i + 1];
        const float aal = anch[3 * i + 2];

        float d2min = 1e30f;
        int   mmin  = 0;
        #pragma unroll 10
        for (int m = 0; m < NM; ++m) {
            float4 a4 = sann[m];
            float dx = ax - a4.x, dy = ay - a4.y;
            float d2 = dx * dx + dy * dy;
            if (d2 < d2min) { d2min = d2; mmin = m; }
        }
        float4 am  = sann[mmin];
        float dxy  = sqrtf(d2min);
        float dal  = fabsf(aal - am.z);
        bool pos = (dxy <= 5.0f) && (dal <= 10.0f);
        bool neg = (dxy >= 7.5f) || (dal >= 15.0f);
        int code = pos ? (int)am.w : (neg ? -1 : -2);

        const int ix = (int)rintf(ax);   // jnp.round = half-to-even
        const int iy = (int)rintf(ay);
        const size_t sidx = (size_t)b * NH * NW + (size_t)iy * NW + ix;
        bool gt;
        if (*flag & 1) gt = ((const uint8_t*)states)[sidx] != 0;
        else           gt = ((const uint32_t*)states)[sidx] != 0u;

        codes[(size_t)b * NA + i] = (code & 0xFFFF) | (gt ? 0x10000 : 0);

        if (pos) {
            const float damp = gt ? 1.0f : 0.1f;
            const float* r = reg + ((size_t)b * NA + i) * 3;
            const float r0 = r[0], r1 = r[1], r2 = r[2];
            const float tdx = am.x - ax, tdy = am.y - ay, tda = am.z - aal;
            const float dxr = fabsf(tdx - r0);
            const float dyr = fabsf(tdy - r1);
            const float lx = (dxr <= (1.0f / 9.0f)) ? 4.5f * dxr * dxr : dxr - (0.5f / 9.0f);
            const float ly = (dyr <= (1.0f / 9.0f)) ? 4.5f * dyr * dyr : dyr - (0.5f / 9.0f);
            atomicAdd(&sred[0], 1.0f);
            atomicAdd(&sred[1], (lx + ly) * damp);
            atomicAdd(&sred[2], fmaxf((fabsf(tda - r2) - 10.0f) / 5.0f, 0.0f) * damp);
        }
    }
    __syncthreads();
    if (t == 0) {
        const int slot = b * PSTRIDE + blockIdx.x;
        P[1 * 8 * PSTRIDE + slot] = sred[0];   // npos
        P[2 * 8 * PSTRIDE + slot] = sred[1];   // xy
        P[3 * 8 * PSTRIDE + slot] = sred[2];   // ang
    }
}

__device__ __forceinline__ float clampp(float p) {
    return fminf(fmaxf(p, 1e-4f), 0.9999f);
}

__global__ __launch_bounds__(256) void focal_cls(
    const float* __restrict__ cls,    // (B, A, C)
    const int*   __restrict__ codes,  // (B, A) packed
    float* __restrict__ P)
{
    const int t = threadIdx.x;
    const int b = blockIdx.y;
    const unsigned j0 = blockIdx.x * (unsigned)CLS_TILE + (unsigned)t;

    const float4* cbase = (const float4*)(cls + (size_t)b * NA * NC);
    const int*    cd    = codes + (size_t)b * NA;

    float sM = 0.0f;   // sum of w * p^2 * log(1-p)  (x -0.05 at end)
    float s2 = 0.0f;   // rare pos-element corrections

    #pragma unroll
    for (int half = 0; half < 2; ++half) {
        unsigned jc[8];
        unsigned ia[8];
        int      pk[8];
        float4   v[8];
        float    wv[8];
        #pragma unroll
        for (int k = 0; k < 8; ++k) {
            unsigned j = j0 + (unsigned)(half * 8 + k) * 256u;
            bool valid = j < (unsigned)J_PER_S;
            jc[k] = valid ? j : (unsigned)(J_PER_S - 1);
            wv[k] = valid ? 1.0f : 0.0f;
            ia[k] = jc[k] / 20u;
            pk[k] = cd[ia[k]];
            v[k]  = cbase[jc[k]];
        }
        #pragma unroll
        for (int k = 0; k < 8; ++k) {
            const int c = (int)((pk[k] << 16) >> 16);   // sext low16
            float w = (c == -2) ? 0.0f : ((pk[k] & 0x10000) ? 1.0f : 0.1f);
            w *= wv[k];
            const int cb = (int)(jc[k] - ia[k] * 20u) * 4;

            const float px = clampp(v[k].x), py = clampp(v[k].y);
            const float pz = clampp(v[k].z), pw = clampp(v[k].w);
            float s4;
            s4  = px * px * __logf(1.0f - px);
            s4 += py * py * __logf(1.0f - py);
            s4 += pz * pz * __logf(1.0f - pz);
            s4 += pw * pw * __logf(1.0f - pw);
            sM += w * s4;

            const int e = c - cb;
            if ((unsigned)e < 4u) {   // rare: this float4 holds the pos target class
                const float pe = (e < 2) ? (e == 0 ? px : py) : (e == 2 ? pz : pw);
                const float om = 1.0f - pe;
                s2 += w * (0.95f * om * om * (-__logf(pe)) - 0.05f * pe * pe * (-__logf(om)));
            }
        }
    }

    float vsum = -0.05f * sM + s2;
    #pragma unroll
    for (int o = 32; o > 0; o >>= 1) vsum += __shfl_down(vsum, o, 64);

    __shared__ float wred[4];
    if ((t & 63) == 0) wred[t >> 6] = vsum;
    __syncthreads();
    if (t == 0) {
        P[b * PSTRIDE + blockIdx.x] = wred[0] + wred[1] + wred[2] + wred[3];  // plain store, no atomic
    }
}

__global__ void focal_final(const float* __restrict__ P, float* __restrict__ out) {
    const int lane = threadIdx.x;   // single wave of 64
    float outc = 0.0f, outx = 0.0f, outa = 0.0f;

    for (int b = 0; b < NB; ++b) {
        float sc = 0.0f;
        for (int j = lane; j < GX_CLS; j += 64) sc += P[b * PSTRIDE + j];
        float sn = 0.0f, sx = 0.0f, sa = 0.0f;
        for (int j = lane; j < GX_ASG; j += 64) {
            sn += P[1 * 8 * PSTRIDE + b * PSTRIDE + j];
            sx += P[2 * 8 * PSTRIDE + b * PSTRIDE + j];
            sa += P[3 * 8 * PSTRIDE + b * PSTRIDE + j];
        }
        #pragma unroll
        for (int o = 32; o > 0; o >>= 1) {
            sc += __shfl_xor(sc, o, 64);
            sn += __shfl_xor(sn, o, 64);
            sx += __shfl_xor(sx, o, 64);
            sa += __shfl_xor(sa, o, 64);
        }
        float np = fmaxf(sn, 1.0f);
        outc += sc / np;
        if (sn > 0.0f) {
            outx += sx / (2.0f * np);
            outa += sa / np;
        }
    }
    if (lane == 0) {
        out[0] = outc / (float)NB;
        out[1] = outx / (float)NB;
        out[2] = outa / (float)NB;
    }
}

extern "C" void kernel_launch(void* const* d_in, const int* in_sizes, int n_in,
                              void* d_out, int out_size, void* d_ws, size_t ws_size,
                              hipStream_t stream) {
    const float* cls    = (const float*)d_in[0];
    const float* reg    = (const float*)d_in[1];
    const float* anch   = (const float*)d_in[2];
    const float* ann    = (const float*)d_in[3];
    const void*  states = d_in[4];

    float* w     = (float*)d_ws;
    int*   flag  = (int*)(w + 32);
    int*   codes = (int*)(w + 1024);
    float* P     = w + 1024 + (size_t)NB * NA;

    hipMemsetAsync(d_ws, 0, 256, stream);   // zero flag
    detect_states_layout<<<1, 256, 0, stream>>>((const uint32_t*)states, flag);

    dim3 gridA(GX_ASG, NB);
    focal_assign<<<gridA, 256, 0, stream>>>(reg, anch, ann, states, flag, P, codes);

    dim3 gridB(GX_CLS, NB);
    focal_cls<<<gridB, 256, 0, stream>>>(cls, codes, P);

    focal_final<<<1, 64, 0, stream>>>(P, (float*)d_out);
}

// Round 4
// 495.823 us; speedup vs baseline: 1.2673x; 1.0485x over previous
//
#include <hip/hip_runtime.h>
#include <stdint.h>

#define NB 8
#define NA 100000
#define NC 80
#define NM 50
#define NH 512
#define NW 512

#define GX      ((NA + 255) / 256)   // 391 blocks per sample
#define PSTRIDE 512                  // partial-plane row stride (>= GX)

// ws layout (float* w = d_ws):
//   w[32] (as int) : states-layout flag
//   P = w + 1024   : partial planes, each [NB][PSTRIDE]:
//     plane 0 = cls_sum, 1 = npos, 2 = xy, 3 = ang

__global__ void detect_states_layout(const uint32_t* __restrict__ w, int* __restrict__ flag) {
    // Packed-uint8 bools -> words with all bytes in {0,1} and value > 1.
    // int32 bools (0/1) and fp32 bools (0x3F800000) never match.
    uint32_t ev = 0;
    for (int j = threadIdx.x; j < 65536; j += 256) {
        uint32_t v = w[j];
        if (((v & 0xFEFEFEFEu) == 0u) && (v > 1u)) ev = 1u;
    }
    if (ev) atomicOr(flag, 1);
}

__device__ __forceinline__ float clampp(float p) {
    return fminf(fmaxf(p, 1e-4f), 0.9999f);
}

__global__ __launch_bounds__(256) void focal_fused(
    const float* __restrict__ cls,   // (B, A, C)
    const float* __restrict__ reg,   // (B, A, 3)
    const float* __restrict__ anch,  // (1, A, 3)
    const float* __restrict__ ann,   // (B, M, 4)
    const void*  __restrict__ states,// (B, 1, H, W) bool
    const int*   __restrict__ flag,
    float* __restrict__ P)
{
    __shared__ float4 sann[NM];
    __shared__ float  swt[256];   // per-anchor row weight: 0 (ignore) or damp
    __shared__ int    scls[256];  // per-anchor target class (-1 if not pos)
    __shared__ float  sred[3];    // npos, xy, ang (LDS atomics, few lanes)
    __shared__ float  wred[4];

    const int t  = threadIdx.x;
    const int b  = blockIdx.y;
    const int i0 = blockIdx.x * 256;
    const int i  = i0 + t;

    if (t < NM) sann[t] = ((const float4*)(ann + (size_t)b * NM * 4))[t];
    if (t < 3)  sred[t] = 0.0f;
    __syncthreads();

    // ---- Phase A: per-anchor assignment + regression losses ----
    float wt   = 0.0f;
    int   tcls = -1;

    if (i < NA) {
        const float ax  = anch[3 * i + 0];
        const float ay  = anch[3 * i + 1];
        const float aal = anch[3 * i + 2];

        float d2min = 1e30f;
        int   mmin  = 0;
        #pragma unroll 10
        for (int m = 0; m < NM; ++m) {
            float4 a4 = sann[m];
            float dx = ax - a4.x, dy = ay - a4.y;
            float d2 = dx * dx + dy * dy;
            if (d2 < d2min) { d2min = d2; mmin = m; }
        }
        float4 am  = sann[mmin];
        float dxy  = sqrtf(d2min);
        float dal  = fabsf(aal - am.z);
        const bool pos = (dxy <= 5.0f) && (dal <= 10.0f);
        const bool neg = (dxy >= 7.5f) || (dal >= 15.0f);

        const int ix = (int)rintf(ax);   // jnp.round = half-to-even
        const int iy = (int)rintf(ay);
        const size_t sidx = (size_t)b * NH * NW + (size_t)iy * NW + ix;
        bool gt;
        if (*flag & 1) gt = ((const uint8_t*)states)[sidx] != 0;
        else           gt = ((const uint32_t*)states)[sidx] != 0u;
        const float damp = gt ? 1.0f : 0.1f;

        wt = (pos || neg) ? damp : 0.0f;
        if (pos) {
            tcls = (int)am.w;
            const float* r = reg + ((size_t)b * NA + i) * 3;
            const float r0 = r[0], r1 = r[1], r2 = r[2];
            const float tdx = am.x - ax, tdy = am.y - ay, tda = am.z - aal;
            const float dxr = fabsf(tdx - r0);
            const float dyr = fabsf(tdy - r1);
            const float lx = (dxr <= (1.0f / 9.0f)) ? 4.5f * dxr * dxr : dxr - (0.5f / 9.0f);
            const float ly = (dyr <= (1.0f / 9.0f)) ? 4.5f * dyr * dyr : dyr - (0.5f / 9.0f);
            atomicAdd(&sred[0], 1.0f);
            atomicAdd(&sred[1], (lx + ly) * damp);
            atomicAdd(&sred[2], fmaxf((fabsf(tda - r2) - 10.0f) / 5.0f, 0.0f) * damp);
        }
    }
    swt[t]  = wt;
    scls[t] = tcls;
    __syncthreads();

    // ---- Phase B: stream this block's contiguous 256x80 chunk ----
    const int n4 = min(256, NA - i0) * (NC / 4);     // float4 count in chunk
    const float4* cbase = (const float4*)(cls + ((size_t)b * NA + i0) * NC);

    float sM = 0.0f;   // sum of w * p^2 * log(1-p)  (x -0.05 at end)
    float s2 = 0.0f;   // rare pos-element corrections

    for (int k0 = 0; k0 < 20; k0 += 4) {
        float4 v[4]; float w4[4]; int tc[4]; int cb[4];
        #pragma unroll
        for (int k = 0; k < 4; ++k) {
            int j = t + (k0 + k) * 256;
            const bool valid = j < n4;
            j = valid ? j : 0;
            const int la = j / 20;                 // float4 never crosses an anchor
            cb[k] = (j - la * 20) * 4;
            tc[k] = scls[la];
            w4[k] = valid ? swt[la] : 0.0f;
            v[k]  = cbase[j];
        }
        #pragma unroll
        for (int k = 0; k < 4; ++k) {
            const float w = w4[k];
            const float px = clampp(v[k].x), py = clampp(v[k].y);
            const float pz = clampp(v[k].z), pw = clampp(v[k].w);
            float s4;
            s4  = px * px * __logf(1.0f - px);
            s4 += py * py * __logf(1.0f - py);
            s4 += pz * pz * __logf(1.0f - pz);
            s4 += pw * pw * __logf(1.0f - pw);
            sM += w * s4;

            const int e = tc[k] - cb[k];
            if ((unsigned)e < 4u) {   // rare: this float4 holds the pos target class
                const float pe = (e < 2) ? (e == 0 ? px : py) : (e == 2 ? pz : pw);
                const float om = 1.0f - pe;
                s2 += w * (0.95f * om * om * (-__logf(pe)) - 0.05f * pe * pe * (-__logf(om)));
            }
        }
    }

    float vsum = -0.05f * sM + s2;
    #pragma unroll
    for (int o = 32; o > 0; o >>= 1) vsum += __shfl_down(vsum, o, 64);
    if ((t & 63) == 0) wred[t >> 6] = vsum;
    __syncthreads();

    if (t == 0) {
        const int slot = b * PSTRIDE + blockIdx.x;
        P[0 * NB * PSTRIDE + slot] = wred[0] + wred[1] + wred[2] + wred[3];
        P[1 * NB * PSTRIDE + slot] = sred[0];
        P[2 * NB * PSTRIDE + slot] = sred[1];
        P[3 * NB * PSTRIDE + slot] = sred[2];
    }
}

__global__ void focal_final(const float* __restrict__ P, float* __restrict__ out) {
    const int lane = threadIdx.x;   // single wave of 64
    float outc = 0.0f, outx = 0.0f, outa = 0.0f;

    for (int b = 0; b < NB; ++b) {
        float sc = 0.0f, sn = 0.0f, sx = 0.0f, sa = 0.0f;
        for (int j = lane; j < GX; j += 64) {
            sc += P[0 * NB * PSTRIDE + b * PSTRIDE + j];
            sn += P[1 * NB * PSTRIDE + b * PSTRIDE + j];
            sx += P[2 * NB * PSTRIDE + b * PSTRIDE + j];
            sa += P[3 * NB * PSTRIDE + b * PSTRIDE + j];
        }
        #pragma unroll
        for (int o = 32; o > 0; o >>= 1) {
            sc += __shfl_xor(sc, o, 64);
            sn += __shfl_xor(sn, o, 64);
            sx += __shfl_xor(sx, o, 64);
            sa += __shfl_xor(sa, o, 64);
        }
        const float np = fmaxf(sn, 1.0f);
        outc += sc / np;
        if (sn > 0.0f) {
            outx += sx / (2.0f * np);
            outa += sa / np;
        }
    }
    if (lane == 0) {
        out[0] = outc / (float)NB;
        out[1] = outx / (float)NB;
        out[2] = outa / (float)NB;
    }
}

extern "C" void kernel_launch(void* const* d_in, const int* in_sizes, int n_in,
                              void* d_out, int out_size, void* d_ws, size_t ws_size,
                              hipStream_t stream) {
    const float* cls    = (const float*)d_in[0];
    const float* reg    = (const float*)d_in[1];
    const float* anch   = (const float*)d_in[2];
    const float* ann    = (const float*)d_in[3];
    const void*  states = d_in[4];

    float* w    = (float*)d_ws;
    int*   flag = (int*)(w + 32);
    float* P    = w + 1024;

    hipMemsetAsync(d_ws, 0, 256, stream);   // zero flag
    detect_states_layout<<<1, 256, 0, stream>>>((const uint32_t*)states, flag);

    dim3 grid(GX, NB);
    focal_fused<<<grid, 256, 0, stream>>>(cls, reg, anch, ann, states, flag, P);

    focal_final<<<1, 64, 0, stream>>>(P, (float*)d_out);
}

// Round 5
// 384.754 us; speedup vs baseline: 1.6332x; 1.2887x over previous
//
#include <hip/hip_runtime.h>
#include <stdint.h>

#define NB 8
#define NA 100000
#define NC 80
#define NM 50
#define NH 512
#define NW 512

#define GX      ((NA + 255) / 256)   // 391 blocks per sample
#define PSTRIDE 512                  // partial-plane row stride (>= GX)

// ws layout (float* w = d_ws):
//   P = w : partial planes, each [NB][PSTRIDE]:
//     plane 0 = cls_sum, 1 = npos, 2 = xy, 3 = ang
// All partial slots are written unconditionally by focal_fused, so no zeroing
// and no global atomics anywhere.

__device__ __forceinline__ float clampp(float p) {
    return fminf(fmaxf(p, 1e-4f), 0.9999f);
}

__global__ __launch_bounds__(256) void focal_fused(
    const float* __restrict__ cls,   // (B, A, C)
    const float* __restrict__ reg,   // (B, A, 3)
    const float* __restrict__ anch,  // (1, A, 3)
    const float* __restrict__ ann,   // (B, M, 4)
    const void*  __restrict__ states,// (B, 1, H, W) bool (1B or 4B elems)
    float* __restrict__ P)
{
    __shared__ float4 sann[NM];
    __shared__ float  swt[256];   // per-anchor row weight: 0 (ignore) or damp
    __shared__ float  sred[3];    // npos, xy, ang (LDS atomics, rare lanes)
    __shared__ float  wred[4];
    __shared__ int    sflag;      // states element width: 1 -> bytes, 0 -> words

    const int t  = threadIdx.x;
    const int b  = blockIdx.y;
    const int i0 = blockIdx.x * 256;
    const int i  = i0 + t;

    // wave 0: detect states layout from its first 2 KB (L2-hot; packed-uint8
    // bools give words with all bytes in {0,1} and value > 1; int32/fp32 never do)
    if (t < 64) {
        const uint32_t* sw = (const uint32_t*)states;
        bool ev = false;
        #pragma unroll
        for (int q = 0; q < 8; ++q) {
            uint32_t v = sw[t + q * 64];
            ev |= ((v & 0xFEFEFEFEu) == 0u) && (v > 1u);
        }
        unsigned long long m = __ballot(ev);
        if (t == 0) sflag = (m != 0ull) ? 1 : 0;
    }
    // wave 1: stage annotations
    if (t >= 64 && t < 64 + NM) sann[t - 64] = ((const float4*)(ann + (size_t)b * NM * 4))[t - 64];
    if (t >= 128 && t < 131) sred[t - 128] = 0.0f;
    __syncthreads();

    // ---- Phase A: per-anchor assignment, regression losses, pos corrections ----
    float wt   = 0.0f;
    float corr = 0.0f;   // pos-element focal correction (moved out of hot loop)

    if (i < NA) {
        const float ax  = anch[3 * i + 0];
        const float ay  = anch[3 * i + 1];
        const float aal = anch[3 * i + 2];

        float d2min = 1e30f;
        int   mmin  = 0;
        #pragma unroll 10
        for (int m = 0; m < NM; ++m) {
            float4 a4 = sann[m];
            float dx = ax - a4.x, dy = ay - a4.y;
            float d2 = dx * dx + dy * dy;
            if (d2 < d2min) { d2min = d2; mmin = m; }
        }
        float4 am  = sann[mmin];
        float dxy  = sqrtf(d2min);
        float dal  = fabsf(aal - am.z);
        const bool pos = (dxy <= 5.0f) && (dal <= 10.0f);
        const bool neg = (dxy >= 7.5f) || (dal >= 15.0f);

        const int ix = (int)rintf(ax);   // jnp.round = half-to-even
        const int iy = (int)rintf(ay);
        const size_t sidx = (size_t)b * NH * NW + (size_t)iy * NW + ix;
        bool gt;
        if (sflag) gt = ((const uint8_t*)states)[sidx] != 0;
        else       gt = ((const uint32_t*)states)[sidx] != 0u;
        const float damp = gt ? 1.0f : 0.1f;

        wt = (pos || neg) ? damp : 0.0f;
        if (pos) {
            const int tcls = (int)am.w;
            // regression losses
            const float* r = reg + ((size_t)b * NA + i) * 3;
            const float r0 = r[0], r1 = r[1], r2 = r[2];
            const float tdx = am.x - ax, tdy = am.y - ay, tda = am.z - aal;
            const float dxr = fabsf(tdx - r0);
            const float dyr = fabsf(tdy - r1);
            const float lx = (dxr <= (1.0f / 9.0f)) ? 4.5f * dxr * dxr : dxr - (0.5f / 9.0f);
            const float ly = (dyr <= (1.0f / 9.0f)) ? 4.5f * dyr * dyr : dyr - (0.5f / 9.0f);
            atomicAdd(&sred[0], 1.0f);
            atomicAdd(&sred[1], (lx + ly) * damp);
            atomicAdd(&sred[2], fmaxf((fabsf(tda - r2) - 10.0f) / 5.0f, 0.0f) * damp);
            // focal correction for the single pos target element:
            // main loop adds damp*0.05*p^2*(-log(1-p)); true term is damp*0.95*(1-p)^2*(-log p)
            const float pe = clampp(cls[((size_t)b * NA + i) * NC + tcls]);
            const float om = 1.0f - pe;
            corr = damp * (0.95f * om * om * (-__logf(pe)) - 0.05f * pe * pe * (-__logf(om)));
        }
    }
    swt[t] = wt;
    __syncthreads();

    // ---- Phase B: stream this block's contiguous 256x80 chunk ----
    const int n4 = min(256, NA - i0) * (NC / 4);     // float4 count in chunk
    const float4* cbase = (const float4*)(cls + ((size_t)b * NA + i0) * NC);

    float sM = 0.0f;   // sum over elements of w * p^2 * log(1-p)   (x -0.05 at end)

    for (int k0 = 0; k0 < 20; k0 += 5) {
        float4 v[5]; float w5[5];
        #pragma unroll
        for (int k = 0; k < 5; ++k) {
            const int j = t + (k0 + k) * 256;
            v[k]  = cbase[min(j, n4 - 1)];   // load clamped; weight uses real j
            w5[k] = swt[j / 20];             // j/20 <= 255; 0 for invalid anchors
        }
        #pragma unroll
        for (int k = 0; k < 5; ++k) {
            const float px = clampp(v[k].x), py = clampp(v[k].y);
            const float pz = clampp(v[k].z), pw = clampp(v[k].w);
            float s4;
            s4  = px * px * __logf(1.0f - px);
            s4 += py * py * __logf(1.0f - py);
            s4 += pz * pz * __logf(1.0f - pz);
            s4 += pw * pw * __logf(1.0f - pw);
            sM = fmaf(w5[k], s4, sM);
        }
    }

    float vsum = fmaf(-0.05f, sM, corr);
    #pragma unroll
    for (int o = 32; o > 0; o >>= 1) vsum += __shfl_down(vsum, o, 64);
    if ((t & 63) == 0) wred[t >> 6] = vsum;
    __syncthreads();

    if (t == 0) {
        const int slot = b * PSTRIDE + blockIdx.x;
        P[0 * NB * PSTRIDE + slot] = wred[0] + wred[1] + wred[2] + wred[3];
        P[1 * NB * PSTRIDE + slot] = sred[0];
        P[2 * NB * PSTRIDE + slot] = sred[1];
        P[3 * NB * PSTRIDE + slot] = sred[2];
    }
}

__global__ void focal_final(const float* __restrict__ P, float* __restrict__ out) {
    const int lane = threadIdx.x;   // single wave of 64
    float outc = 0.0f, outx = 0.0f, outa = 0.0f;

    for (int b = 0; b < NB; ++b) {
        float sc = 0.0f, sn = 0.0f, sx = 0.0f, sa = 0.0f;
        for (int j = lane; j < GX; j += 64) {
            sc += P[0 * NB * PSTRIDE + b * PSTRIDE + j];
            sn += P[1 * NB * PSTRIDE + b * PSTRIDE + j];
            sx += P[2 * NB * PSTRIDE + b * PSTRIDE + j];
            sa += P[3 * NB * PSTRIDE + b * PSTRIDE + j];
        }
        #pragma unroll
        for (int o = 32; o > 0; o >>= 1) {
            sc += __shfl_xor(sc, o, 64);
            sn += __shfl_xor(sn, o, 64);
            sx += __shfl_xor(sx, o, 64);
            sa += __shfl_xor(sa, o, 64);
        }
        const float np = fmaxf(sn, 1.0f);
        outc += sc / np;
        if (sn > 0.0f) {
            outx += sx / (2.0f * np);
            outa += sa / np;
        }
    }
    if (lane == 0) {
        out[0] = outc / (float)NB;
        out[1] = outx / (float)NB;
        out[2] = outa / (float)NB;
    }
}

extern "C" void kernel_launch(void* const* d_in, const int* in_sizes, int n_in,
                              void* d_out, int out_size, void* d_ws, size_t ws_size,
                              hipStream_t stream) {
    const float* cls    = (const float*)d_in[0];
    const float* reg    = (const float*)d_in[1];
    const float* anch   = (const float*)d_in[2];
    const float* ann    = (const float*)d_in[3];
    const void*  states = d_in[4];

    float* P = (float*)d_ws;

    dim3 grid(GX, NB);
    focal_fused<<<grid, 256, 0, stream>>>(cls, reg, anch, ann, states, P);

    focal_final<<<1, 64, 0, stream>>>(P, (float*)d_out);
}